// Round 5
// baseline (4662.373 us; speedup 1.0000x reference)
//
#include <hip/hip_runtime.h>

#define LL 1024
#define NBLK 256
#define NTHR 512
#define SMEM_BYTES (73728 + 8)

typedef __attribute__((ext_vector_type(8))) __bf16 bf16x8;
typedef __attribute__((ext_vector_type(4))) __bf16 bf16x4;
typedef __attribute__((ext_vector_type(16))) float f32x16;

// All inputs/outputs are FLOAT32. MFMA core runs bf16 (f32 accumulate).
__device__ __bf16 g_trg[128 * 1024 * 256];     // 64 MB
__device__ __bf16 g_wih[4096 * 256];           // 2 MB
__device__ __bf16 g_whh[4096 * 1024];          // 8 MB
__device__ __bf16 g_wout[256 * 1024];          // 0.5 MB
// Write-once h ring: [t(1024)][group(4)][kc(128)][m(32)][8] bf16 = 268 MB.
// Fresh addresses every step -> readers use plain cached loads, no invalidates.
// Cross-replay staleness handled by entry fence + flag protocol.
// Also read by the deferred out_proj kernel after the persistent kernel ends.
__device__ __bf16 g_ring[(size_t)1024 * 4 * 32768];
// ONE flag per (step, group, block): [t][p][q]. Set by the last wave of the
// block to drain its h stores (detected via native LDS ds_add_rtn). Polled by
// wave 0 only of each reader block (256 pollers device-wide, was 2048).
__device__ unsigned int g_flag[1024 * 4 * 64];   // 1 MB, zeroed each launch

__device__ __forceinline__ float sigm(float x) { return 1.f / (1.f + __expf(-x)); }
__device__ __forceinline__ float tanh_(float x) {
  x = fminf(fmaxf(x, -15.f), 15.f);
  float e = __expf(2.f * x);
  return (e - 1.f) / (e + 1.f);
}

__global__ void zero_flag() {
  int i = blockIdx.x * blockDim.x + threadIdx.x;   // grid 1024x256 = 262144
  g_flag[i] = 0u;
}

__global__ void cvt4(const float* __restrict__ s, __bf16* __restrict__ d, int n4) {
  int i = blockIdx.x * blockDim.x + threadIdx.x;
  if (i < n4) {
    float4 v = ((const float4*)s)[i];
    bf16x4 o;
    o[0] = (__bf16)v.x; o[1] = (__bf16)v.y; o[2] = (__bf16)v.z; o[3] = (__bf16)v.w;
    ((bf16x4*)d)[i] = o;
  }
}

// Persistent LSTM decoder. Grid: 256 blocks = P(4 batch groups of 32 rows) x
// Q(64 col-blocks of 16 h-cols). Block: 8 waves, 8-way K-split: wave w owns
// h-k [w*128,(w+1)*128) + x-k [w*32,(w+1)*32), computes both 32-col tiles from
// one A fragment. SINGLE-PHASE reduction: both accs dumped into zp[8][32][72]
// (73.7 KB dynamic LDS; gfx950 allows up to 160 KB/WG), 2 barriers/step.
// Exchange: each wave drains own h stores (vmcnt0) then ds_add_rtn a LDS
// counter; 8th wave sets the block's ONE flag. Reader wave0 polls the 64
// per-block flags (one/lane) and broadcasts 'go' via LDS; waves 1-7 spin on
// LDS (no LLC traffic). gid swizzle co-locates each group on 2 XCDs.
__global__ __launch_bounds__(NTHR, 2) void lstm_persist(
    const float* __restrict__ b_ih, const float* __restrict__ b_hh)
{
  extern __shared__ __align__(16) char smem[];
  float (*zp)[32][72] = (float (*)[32][72])smem;          // 8*32*72*4 = 73728 B
  unsigned* ctrl = (unsigned*)(smem + 73728);             // [0]=done_cnt [1]=go

  const int tid = threadIdx.x;
  const int lane = tid & 63;
  const int w = tid >> 6;        // wave 0..7 = K-split id
  const int gid = blockIdx.x;
  const int p = (gid & 7) >> 1;                // batch group -> XCD pair {2p,2p+1}
  const int q = ((gid >> 3) << 1) | (gid & 1); // col block 0..63
  const int m = lane & 31;
  const int khalf = (lane >> 5) << 3;   // 0 or 8

  // One-time invalidate of stale L1/L2 lines from a previous replay.
  __builtin_amdgcn_fence(__ATOMIC_ACQUIRE, "agent");

  if (tid < 2) ctrl[tid] = 0u;

  // ---- B fragments (weights) -> registers, kept for whole kernel ----
  // tile0 (acc0): block-local gate cols = i(m<16), f(m>=16)
  // tile1 (acc1): g(m<16), o(m>=16)
  const int colb = (q << 4) + (m & 15);
  const int grow0 = ((m >> 4) << 10) + colb;         // gate 0/1 row
  const int grow1 = ((2 + (m >> 4)) << 10) + colb;   // gate 2/3 row

  bf16x8 bR0[8], bR1[8], bX0[2], bX1[2];
  #pragma unroll
  for (int s = 0; s < 8; ++s) {            // recurrent slices, k in [w*128, ...)
    int k = (w << 7) + (s << 4) + khalf;
    bR0[s] = *(const bf16x8*)(g_whh + grow0 * 1024 + k);
    bR1[s] = *(const bf16x8*)(g_whh + grow1 * 1024 + k);
  }
  #pragma unroll
  for (int s = 0; s < 2; ++s) {            // input slices, k in [w*32, ...)
    int k = (w << 5) + (s << 4) + khalf;
    bX0[s] = *(const bf16x8*)(g_wih + grow0 * 256 + k);
    bX1[s] = *(const bf16x8*)(g_wih + grow1 * 256 + k);
  }

  // ---- elementwise role: thread <-> (batch row em, h-col ej) ----
  const int em = tid >> 4;             // 0..31
  const int ej = tid & 15;             // 0..15
  const int hcol = (q << 4) + ej;
  float bias_i = b_ih[hcol]        + b_hh[hcol];
  float bias_f = b_ih[1024 + hcol] + b_hh[1024 + hcol];
  float bias_g = b_ih[2048 + hcol] + b_hh[2048 + hcol];
  float bias_o = b_ih[3072 + hcol] + b_hh[3072 + hcol];

  // ring element chunk for this thread's h value
  const int rc = (q << 1) + (ej >> 3);
  const int ejlo = ej & 7;

  // writer columns in zp (interleaved so reader gets float2 pairs)
  const int wcol = ((m & 15) << 1) + (m >> 4);    // acc0: i even, f odd
  // acc1 goes at 32 + wcol (g even, o odd)

  float cst = 0.f;
  f32x16 acc0, acc1;
  #pragma unroll
  for (int r = 0; r < 16; ++r) { acc0[r] = 0.f; acc1[r] = 0.f; }

  const size_t trgbase = (size_t)(((p << 5) + m) << 10);
  __syncthreads();    // ctrl init visible

  #pragma unroll 1
  for (int t = 0; t < LL; ++t) {
    // ---- pre-wait: x-projection MFMAs (h-independent) ----
    {
      int tx = (t == 0) ? 0 : (t - 1);   // teacher forcing shift
      const __bf16* trow = g_trg + ((trgbase + tx) << 8);
      bf16x8 ax0 = *(const bf16x8*)(trow + (w << 5) + khalf);
      bf16x8 ax1 = *(const bf16x8*)(trow + (w << 5) + 16 + khalf);
      acc0 = __builtin_amdgcn_mfma_f32_32x32x16_bf16(ax0, bX0[0], acc0, 0, 0, 0);
      acc1 = __builtin_amdgcn_mfma_f32_32x32x16_bf16(ax0, bX1[0], acc1, 0, 0, 0);
      acc0 = __builtin_amdgcn_mfma_f32_32x32x16_bf16(ax1, bX0[1], acc0, 0, 0, 0);
      acc1 = __builtin_amdgcn_mfma_f32_32x32x16_bf16(ax1, bX1[1], acc1, 0, 0, 0);
    }
    if (t > 0) {
      // ---- wave0 polls the 64 per-block flags; others spin on LDS 'go' ----
      if (w == 0) {
        unsigned int* fp = g_flag + ((((t - 1) << 2) + p) << 6) + lane;
        unsigned f = __hip_atomic_load(fp, __ATOMIC_RELAXED, __HIP_MEMORY_SCOPE_AGENT);
        int spins = 0;
        while (__any(f == 0u)) {
          f = __hip_atomic_load(fp, __ATOMIC_RELAXED, __HIP_MEMORY_SCOPE_AGENT);
          if (++spins > 2000000) break;   // safety bailout
        }
        ((volatile unsigned*)ctrl)[1] = (unsigned)t;   // broadcast 'go'
      } else {
        volatile unsigned* gp = ((volatile unsigned*)ctrl) + 1;
        int spins = 0;
        while (*gp < (unsigned)t) {
          if (++spins > 200000000) break; // safety bailout
        }
      }
      asm volatile("" ::: "memory");      // no hoisting of ring loads above spin
      // ---- recurrent GEMM: z += h_{t-1} @ w_hh^T (cached ring loads) ----
      const __bf16* rrd = g_ring + (size_t)(t - 1) * 131072 + (p << 15);
      #pragma unroll
      for (int s = 0; s < 8; ++s) {
        int k0 = (w << 7) + (s << 4);
        bf16x8 a = *(const bf16x8*)(rrd + ((k0 + khalf) << 5) + (m << 3));
        acc0 = __builtin_amdgcn_mfma_f32_32x32x16_bf16(a, bR0[s], acc0, 0, 0, 0);
        acc1 = __builtin_amdgcn_mfma_f32_32x32x16_bf16(a, bR1[s], acc1, 0, 0, 0);
      }
    }
    // ---- single-phase dump: both accs ----
    // (C/D: col=lane&31, row=(r&3)+8*(r>>2)+4*(lane>>5))
    #pragma unroll
    for (int r = 0; r < 16; ++r) {
      int row = (r & 3) + ((r >> 2) << 3) + ((lane >> 5) << 2);
      zp[w][row][wcol]      = acc0[r];  acc0[r] = 0.f;
      zp[w][row][32 + wcol] = acc1[r];  acc1[r] = 0.f;
    }
    __syncthreads();     // (B) all partials visible

    // ---- gates + state update; publish h directly from registers ----
    {
      float zi = bias_i, zf = bias_f, zg = bias_g, zo = bias_o;
      #pragma unroll
      for (int s = 0; s < 8; ++s) {
        float2 v0 = *(const float2*)&zp[s][em][ej << 1];
        float2 v1 = *(const float2*)&zp[s][em][32 + (ej << 1)];
        zi += v0.x; zf += v0.y; zg += v1.x; zo += v1.y;
      }
      cst = sigm(zf) * cst + sigm(zi) * tanh_(zg);
      float h = sigm(zo) * tanh_(cst);
      __bf16 hb = (__bf16)h;
      unsigned hu = (unsigned)*(unsigned short*)&hb;
      unsigned pu = (unsigned)__shfl_xor((int)hu, 1);
      if ((ej & 1) == 0) {
        unsigned word = hu | (pu << 16);   // little-endian: even ejlo at low half
        unsigned* dst = (unsigned*)(g_ring + (size_t)t * 131072 + (p << 15))
                        + (rc << 7) + (em << 2) + (ejlo >> 1);
        __hip_atomic_store(dst, word, __ATOMIC_RELAXED, __HIP_MEMORY_SCOPE_AGENT);
      }
    }
    // ---- per-wave drain; last-drained wave sets the block's single flag ----
    asm volatile("s_waitcnt vmcnt(0)" ::: "memory");  // h stores at coherence point
    if (lane == 0) {
      unsigned old = atomicAdd(&ctrl[0], 1u);         // native ds_add_rtn_u32
      if (old == (unsigned)((t << 3) + 7)) {          // 8th wave this step
        __hip_atomic_store(g_flag + (((t << 2) + p) << 6) + q, 1u,
                           __ATOMIC_RELAXED, __HIP_MEMORY_SCOPE_AGENT);
      }
    }
    __syncthreads();     // (E) zp reads done; buffer free for next step
  }
}

// Deferred out-projection: out[b,t,:] = h_t[b,:] @ w_out^T + b_out.
// Grid: 256 blocks = tcb(8 chunks of 128 t) x oc(8 out-col tiles of 32) x p(4).
// 8 waves = 8-way K-split; wave w holds w_out fragments for k in
// [w*128,(w+1)*128) in REGISTERS (loaded once). A-fragments read directly from
// the ring with 1-step prefetch. Single-phase LDS reduce, coalesced stores.
__global__ __launch_bounds__(NTHR, 2) void out_proj(
    const float* __restrict__ b_out, float* __restrict__ out)
{
  const int tid = threadIdx.x;
  const int lane = tid & 63;
  const int w = tid >> 6;
  const int m = lane & 31;
  const int khalf = (lane >> 5) << 3;
  const int gid = blockIdx.x;      // 256
  const int p = gid & 3;
  const int oc = (gid >> 2) & 7;   // out-col tile (32 cols)
  const int tcb = gid >> 5;        // t chunk 0..7 (128 t each)

  __shared__ float zp[8][32][36];  // 36,864 B; 2-way max (free)

  // ---- w_out B fragments in registers for the whole kernel ----
  bf16x8 bo[8];
  #pragma unroll
  for (int s = 0; s < 8; ++s)
    bo[s] = *(const bf16x8*)(g_wout + ((oc << 5) + m) * 1024 + (w << 7) + (s << 4) + khalf);

  const int em = tid >> 4;         // 0..31 batch row (elementwise role)
  const int c  = tid & 15;         // out cols c and c+16 within tile
  const float ob0 = b_out[(oc << 5) + c];
  const float ob1 = b_out[(oc << 5) + 16 + c];

  const int t0 = tcb << 7;
  bf16x8 a[8], an[8];
  {
    const __bf16* rrd = g_ring + (size_t)t0 * 131072 + (p << 15);
    #pragma unroll
    for (int s = 0; s < 8; ++s)
      a[s] = *(const bf16x8*)(rrd + (((w << 7) + (s << 4) + khalf) << 5) + (m << 3));
  }

  #pragma unroll 1
  for (int ti = 0; ti < 128; ++ti) {
    const int t = t0 + ti;
    // prefetch next t's A fragments (hides LLC RTT under reduce phases)
    if (ti < 127) {
      const __bf16* rrd = g_ring + (size_t)(t + 1) * 131072 + (p << 15);
      #pragma unroll
      for (int s = 0; s < 8; ++s)
        an[s] = *(const bf16x8*)(rrd + (((w << 7) + (s << 4) + khalf) << 5) + (m << 3));
    }
    f32x16 acc;
    #pragma unroll
    for (int r = 0; r < 16; ++r) acc[r] = 0.f;
    #pragma unroll
    for (int s = 0; s < 8; ++s)
      acc = __builtin_amdgcn_mfma_f32_32x32x16_bf16(a[s], bo[s], acc, 0, 0, 0);
    #pragma unroll
    for (int r = 0; r < 16; ++r) {
      int row = (r & 3) + ((r >> 2) << 3) + ((lane >> 5) << 2);
      zp[w][row][m] = acc[r];
    }
    __syncthreads();
    float o0 = ob0, o1 = ob1;
    #pragma unroll
    for (int s = 0; s < 8; ++s) {
      o0 += zp[s][em][c];
      o1 += zp[s][em][16 + c];
    }
    float* orow = out + ((((size_t)((p << 5) + em) << 10) + t) << 8) + (oc << 5);
    orow[c]      = o0;
    orow[16 + c] = o1;
    __syncthreads();     // WAR: reads done before next iteration's dump
    #pragma unroll
    for (int s = 0; s < 8; ++s) a[s] = an[s];
  }
}

extern "C" void kernel_launch(void* const* d_in, const int* in_sizes, int n_in,
                              void* d_out, int out_size, void* d_ws, size_t ws_size,
                              hipStream_t stream) {
  const float* trg   = (const float*)d_in[0];
  const float* w_ih  = (const float*)d_in[1];
  const float* w_hh  = (const float*)d_in[2];
  const float* b_ih  = (const float*)d_in[3];
  const float* b_hh  = (const float*)d_in[4];
  const float* w_out = (const float*)d_in[5];
  const float* b_out = (const float*)d_in[6];

  static int attr_set = 0;
  if (!attr_set) {
    hipFuncSetAttribute((const void*)lstm_persist,
                        hipFuncAttributeMaxDynamicSharedMemorySize, SMEM_BYTES);
    attr_set = 1;
  }

  __bf16 *p_trg, *p_wih, *p_whh, *p_wout;
  hipGetSymbolAddress((void**)&p_trg,  HIP_SYMBOL(g_trg));
  hipGetSymbolAddress((void**)&p_wih,  HIP_SYMBOL(g_wih));
  hipGetSymbolAddress((void**)&p_whh,  HIP_SYMBOL(g_whh));
  hipGetSymbolAddress((void**)&p_wout, HIP_SYMBOL(g_wout));

  cvt4<<<dim3(33554432 / 4 / 256), dim3(256), 0, stream>>>(trg,   p_trg,  33554432 / 4);
  cvt4<<<dim3(1048576  / 4 / 256), dim3(256), 0, stream>>>(w_ih,  p_wih,  1048576  / 4);
  cvt4<<<dim3(4194304  / 4 / 256), dim3(256), 0, stream>>>(w_hh,  p_whh,  4194304  / 4);
  cvt4<<<dim3(262144   / 4 / 256), dim3(256), 0, stream>>>(w_out, p_wout, 262144   / 4);
  zero_flag<<<dim3(1024), dim3(256), 0, stream>>>();

  lstm_persist<<<dim3(NBLK), dim3(NTHR), SMEM_BYTES, stream>>>(b_ih, b_hh);
  out_proj<<<dim3(NBLK), dim3(NTHR), 0, stream>>>(b_out, (float*)d_out);
}